// Round 6
// baseline (748.102 us; speedup 1.0000x reference)
//
#include <hip/hip_runtime.h>

#define N_NODES 100000
#define N_EDGES 3200000
#define D 256
#define CAP 64          // padded-CSR capacity; P(deg>64)~4e-6/row, overflow list covers
#define OVF_MAX 4096

#define GEMM_BLOCKS (N_NODES / 16)      // 6250
#define SCAT_BLOCKS (N_EDGES / (256*4)) // 3125, one pass, 4 edges/thread
#define TOTAL_BLOCKS (GEMM_BLOCKS + SCAT_BLOCKS)

typedef __attribute__((ext_vector_type(8))) short bf16x8;
typedef __attribute__((ext_vector_type(4))) float f32x4;
typedef __attribute__((ext_vector_type(2))) float f32x2;

// ---------------- static device scratch (rebuilt every call) ----------------
__device__ unsigned short g_wt[(size_t)D * D];              // W^T bf16 [n][k]
__device__ unsigned short g_support[(size_t)N_NODES * D];   // 51.2 MB bf16
__device__ int   g_cursor[N_NODES];                         // per-row degree
__device__ int2  g_pad[(size_t)N_NODES * CAP];              // 51.2 MB {col, val}
__device__ int   g_novf;
__device__ int   g_ovf_row[OVF_MAX];
__device__ int2  g_ovf_edge[OVF_MAX];

// fp32 -> bf16 round-to-nearest-even
__device__ __forceinline__ unsigned short f2bf(float f) {
    unsigned u = __float_as_uint(f);
    unsigned r = u + 0x7fffu + ((u >> 16) & 1u);
    return (unsigned short)(r >> 16);
}

// ------------------------------------------ setup: W^T bf16 + zero cursors
__global__ void setup_kernel(const float* __restrict__ W) {
    const int tid = threadIdx.x;
    if (blockIdx.x < 64) {
        int k0 = blockIdx.x * 4;
        #pragma unroll
        for (int j = 0; j < 4; ++j) {
            int k = k0 + j;
            g_wt[(size_t)tid * D + k] = f2bf(W[(size_t)k * D + tid]);
        }
    }
    for (int i = blockIdx.x * blockDim.x + tid; i < N_NODES;
         i += gridDim.x * blockDim.x)
        g_cursor[i] = 0;
    if (blockIdx.x == 0 && tid == 0) g_novf = 0;
}

// ------------------------------------- fused: MFMA GEMM || padded scatter
// Roles interleaved (b%3==0 -> scatter) so both populations are co-resident
// from dispatch 0: scatter's memory stalls hide under GEMM's MFMA work.
__launch_bounds__(256)
__global__ void gemm_scatter_kernel(const float* __restrict__ x,
                                    const float* __restrict__ edge_val,
                                    const int* __restrict__ edge_row,
                                    const int* __restrict__ edge_col) {
    __shared__ float tile[4][16][68];
    const int tid = threadIdx.x;
    const int b = blockIdx.x;
    const bool is_scatter = (b % 3 == 0) && (b / 3 < SCAT_BLOCKS);

    if (!is_scatter) {
        // ---------------- GEMM: per-wave 16x64 tile, K=256, inline fp32->bf16
        const int gb = (b % 3 == 0) ? (b - b / 3 - 1 + 1) /*unreachable*/ 
                                    : (b - b / 3 - 1);
        const int gemm_id = (b % 3 == 0) ? (SCAT_BLOCKS + (b / 3) - SCAT_BLOCKS)
                                         : gb;  // simplified below
        const int g = (b % 3 == 0) ? 0 : (b - b / 3 - 1);
        (void)gemm_id; (void)gb;
        const int wave = tid >> 6;
        const int lane = tid & 63;
        const int m0   = g * 16;
        const int n0   = wave * 64;
        const int lm   = lane & 15;
        const int q    = lane >> 4;

        const unsigned short* B = g_wt;
        f32x4 acc0 = {}, acc1 = {}, acc2 = {}, acc3 = {};

        #pragma unroll
        for (int k0 = 0; k0 < D; k0 += 32) {
            const float* Arow = &x[(size_t)(m0 + lm) * D + k0 + q * 8];
            float4 f0 = *(const float4*)&Arow[0];
            float4 f1 = *(const float4*)&Arow[4];
            union { bf16x8 v; unsigned short u[8]; } au;
            au.u[0] = f2bf(f0.x); au.u[1] = f2bf(f0.y);
            au.u[2] = f2bf(f0.z); au.u[3] = f2bf(f0.w);
            au.u[4] = f2bf(f1.x); au.u[5] = f2bf(f1.y);
            au.u[6] = f2bf(f1.z); au.u[7] = f2bf(f1.w);

            bf16x8 b0 = *(const bf16x8*)&B[(size_t)(n0 +  0 + lm) * D + k0 + q * 8];
            bf16x8 b1 = *(const bf16x8*)&B[(size_t)(n0 + 16 + lm) * D + k0 + q * 8];
            bf16x8 b2 = *(const bf16x8*)&B[(size_t)(n0 + 32 + lm) * D + k0 + q * 8];
            bf16x8 b3 = *(const bf16x8*)&B[(size_t)(n0 + 48 + lm) * D + k0 + q * 8];
            acc0 = __builtin_amdgcn_mfma_f32_16x16x32_bf16(au.v, b0, acc0, 0, 0, 0);
            acc1 = __builtin_amdgcn_mfma_f32_16x16x32_bf16(au.v, b1, acc1, 0, 0, 0);
            acc2 = __builtin_amdgcn_mfma_f32_16x16x32_bf16(au.v, b2, acc2, 0, 0, 0);
            acc3 = __builtin_amdgcn_mfma_f32_16x16x32_bf16(au.v, b3, acc3, 0, 0, 0);
        }

        #pragma unroll
        for (int r = 0; r < 4; ++r) {
            tile[wave][q * 4 + r][ 0 + lm] = acc0[r];
            tile[wave][q * 4 + r][16 + lm] = acc1[r];
            tile[wave][q * 4 + r][32 + lm] = acc2[r];
            tile[wave][q * 4 + r][48 + lm] = acc3[r];
        }
        const int row  = lane >> 2;
        const int cseg = (lane & 3) * 16;
        unsigned short outv[16];
        #pragma unroll
        for (int j = 0; j < 16; ++j)
            outv[j] = f2bf(tile[wave][row][cseg + j]);
        unsigned short* dst = &g_support[(size_t)(m0 + row) * D + n0 + cseg];
        *(uint4*)&dst[0] = *(const uint4*)&outv[0];
        *(uint4*)&dst[8] = *(const uint4*)&outv[8];
    } else {
        // ---------------- scatter: 4 edges/thread, vector loads, batched atomics
        const int sb = b / 3;
        const int base = (sb * 256 + tid) * 4;
        int4   r4 = *(const int4*)&edge_row[base];
        int4   c4 = *(const int4*)&edge_col[base];
        float4 v4 = *(const float4*)&edge_val[base];
        // 4 independent atomics in flight
        int s0 = atomicAdd(&g_cursor[r4.x], 1);
        int s1 = atomicAdd(&g_cursor[r4.y], 1);
        int s2 = atomicAdd(&g_cursor[r4.z], 1);
        int s3 = atomicAdd(&g_cursor[r4.w], 1);
        int2 p0 = { c4.x, __float_as_int(v4.x) };
        int2 p1 = { c4.y, __float_as_int(v4.y) };
        int2 p2 = { c4.z, __float_as_int(v4.z) };
        int2 p3 = { c4.w, __float_as_int(v4.w) };
        if (s0 < CAP) g_pad[(size_t)r4.x * CAP + s0] = p0;
        else { int o = atomicAdd(&g_novf, 1); if (o < OVF_MAX) { g_ovf_row[o] = r4.x; g_ovf_edge[o] = p0; } }
        if (s1 < CAP) g_pad[(size_t)r4.y * CAP + s1] = p1;
        else { int o = atomicAdd(&g_novf, 1); if (o < OVF_MAX) { g_ovf_row[o] = r4.y; g_ovf_edge[o] = p1; } }
        if (s2 < CAP) g_pad[(size_t)r4.z * CAP + s2] = p2;
        else { int o = atomicAdd(&g_novf, 1); if (o < OVF_MAX) { g_ovf_row[o] = r4.z; g_ovf_edge[o] = p2; } }
        if (s3 < CAP) g_pad[(size_t)r4.w * CAP + s3] = p3;
        else { int o = atomicAdd(&g_novf, 1); if (o < OVF_MAX) { g_ovf_row[o] = r4.w; g_ovf_edge[o] = p3; } }
    }
}

// ---------------------------------------------------------------- SpMM
// One 128-thread block per row; thread t owns features 2t, 2t+1.
__launch_bounds__(128)
__global__ void spmm_kernel(float* __restrict__ out) {
    const int r = blockIdx.x;
    const int t = threadIdx.x;
    const int deg = g_cursor[r];
    const int dpad = min(deg, CAP);
    const long long* rowp = (const long long*)&g_pad[(size_t)r * CAP];
    const unsigned* sup = (const unsigned*)g_support;

    float a0 = 0.f, a1 = 0.f;
    int i = 0;
    for (; i + 3 < dpad; i += 4) {
        long long q0 = __builtin_nontemporal_load(&rowp[i]);
        long long q1 = __builtin_nontemporal_load(&rowp[i + 1]);
        long long q2 = __builtin_nontemporal_load(&rowp[i + 2]);
        long long q3 = __builtin_nontemporal_load(&rowp[i + 3]);
        unsigned p0 = sup[(size_t)(int)q0 * (D / 2) + t];
        unsigned p1 = sup[(size_t)(int)q1 * (D / 2) + t];
        unsigned p2 = sup[(size_t)(int)q2 * (D / 2) + t];
        unsigned p3 = sup[(size_t)(int)q3 * (D / 2) + t];
        float v0 = __int_as_float((int)(q0 >> 32));
        float v1 = __int_as_float((int)(q1 >> 32));
        float v2 = __int_as_float((int)(q2 >> 32));
        float v3 = __int_as_float((int)(q3 >> 32));
        a0 += v0 * __uint_as_float(p0 << 16);
        a1 += v0 * __uint_as_float(p0 & 0xffff0000u);
        a0 += v1 * __uint_as_float(p1 << 16);
        a1 += v1 * __uint_as_float(p1 & 0xffff0000u);
        a0 += v2 * __uint_as_float(p2 << 16);
        a1 += v2 * __uint_as_float(p2 & 0xffff0000u);
        a0 += v3 * __uint_as_float(p3 << 16);
        a1 += v3 * __uint_as_float(p3 & 0xffff0000u);
    }
    for (; i < dpad; ++i) {
        long long q0 = __builtin_nontemporal_load(&rowp[i]);
        float v0 = __int_as_float((int)(q0 >> 32));
        unsigned p0 = sup[(size_t)(int)q0 * (D / 2) + t];
        a0 += v0 * __uint_as_float(p0 << 16);
        a1 += v0 * __uint_as_float(p0 & 0xffff0000u);
    }
    if (deg > CAP) {                       // correctness fallback (near-empty)
        int novf = min(g_novf, OVF_MAX);
        for (int j = 0; j < novf; ++j) {
            if (g_ovf_row[j] == r) {
                int2 e0 = g_ovf_edge[j];
                float v0 = __int_as_float(e0.y);
                unsigned p0 = sup[(size_t)e0.x * (D / 2) + t];
                a0 += v0 * __uint_as_float(p0 << 16);
                a1 += v0 * __uint_as_float(p0 & 0xffff0000u);
            }
        }
    }
    f32x2 o;
    o.x = fmaxf(a0, 0.f);
    o.y = fmaxf(a1, 0.f);
    __builtin_nontemporal_store(o, (f32x2*)&out[(size_t)r * D + 2 * t]);
}

// ---------------------------------------------------------------- launcher
extern "C" void kernel_launch(void* const* d_in, const int* in_sizes, int n_in,
                              void* d_out, int out_size, void* d_ws, size_t ws_size,
                              hipStream_t stream) {
    const float* x        = (const float*)d_in[0];
    const float* weight   = (const float*)d_in[1];
    const float* edge_val = (const float*)d_in[2];
    const int*   edge_row = (const int*)d_in[3];
    const int*   edge_col = (const int*)d_in[4];
    float* out = (float*)d_out;

    setup_kernel<<<160, 256, 0, stream>>>(weight);
    gemm_scatter_kernel<<<TOTAL_BLOCKS, 256, 0, stream>>>(
        x, edge_val, edge_row, edge_col);
    spmm_kernel<<<N_NODES, 128, 0, stream>>>(out);
}

// Round 7
// 710.239 us; speedup vs baseline: 1.0533x; 1.0533x over previous
//
#include <hip/hip_runtime.h>

#define N_NODES 100000
#define N_EDGES 3200000
#define D 256
#define CAP 64            // padded-CSR row capacity (mean deg 32)
#define OVF_MAX 8192

#define RPB 256           // rows per bucket
#define NBUCK 391         // ceil(N_NODES / RPB)
#define CAPB 11264        // bucket capacity (mean 8192, +34 sigma)
#define CHUNK 8192        // edges per bin block
#define NBLK_A ((N_EDGES + CHUNK - 1) / CHUNK)   // 391

#define GEMM_BLOCKS (N_NODES / 16)               // 6250

typedef __attribute__((ext_vector_type(8))) short bf16x8;
typedef __attribute__((ext_vector_type(4))) float f32x4;
typedef __attribute__((ext_vector_type(2))) float f32x2;

// ---------------- static device scratch (rebuilt every call) ----------------
__device__ unsigned short g_wt[(size_t)D * D];              // W^T bf16 [n][k]
__device__ unsigned short g_support[(size_t)N_NODES * D];   // 51.2 MB bf16
__device__ int   g_cursor[N_NODES];                         // per-row degree
__device__ int2  g_pad[(size_t)N_NODES * CAP];              // 51.2 MB {col,val}
__device__ int   g_bucket_cur[NBUCK];                       // bucket fill cursors
__device__ int2  g_binned[(size_t)NBUCK * CAPB];            // 35.2 MB bucketed edges
__device__ int   g_novf;
__device__ int   g_ovf_row[OVF_MAX];
__device__ int2  g_ovf_edge[OVF_MAX];

// fp32 -> bf16 round-to-nearest-even
__device__ __forceinline__ unsigned short f2bf(float f) {
    unsigned u = __float_as_uint(f);
    unsigned r = u + 0x7fffu + ((u >> 16) & 1u);
    return (unsigned short)(r >> 16);
}

// ------------------------------------------ setup: W^T bf16 + zero cursors
__global__ void setup_kernel(const float* __restrict__ W) {
    const int tid = threadIdx.x;
    if (blockIdx.x < 64) {
        int k0 = blockIdx.x * 4;
        #pragma unroll
        for (int j = 0; j < 4; ++j) {
            int k = k0 + j;
            g_wt[(size_t)tid * D + k] = f2bf(W[(size_t)k * D + tid]);
        }
    }
    for (int i = blockIdx.x * blockDim.x + tid; i < NBUCK;
         i += gridDim.x * blockDim.x)
        g_bucket_cur[i] = 0;
    if (blockIdx.x == 0 && tid == 0) g_novf = 0;
}

// ------------------------------------------------- phase A: bin by row>>8
// Per block: count chunk's edges per bucket in LDS, reserve global space with
// one atomic per (block,bucket), stage records bucket-sorted in LDS, flush as
// contiguous bursts. Converts 6.4M random fabric transactions into ~150K
// atomics + burst writes.
__launch_bounds__(256)
__global__ void bin_kernel(const float* __restrict__ edge_val,
                           const int* __restrict__ edge_row,
                           const int* __restrict__ edge_col) {
    __shared__ int2 rec[CHUNK];          // 64 KB staging
    __shared__ int cnt[NBUCK];
    __shared__ int pre[NBUCK + 1];
    __shared__ int bas[NBUCK];
    const int tid = threadIdx.x;
    const int e0 = blockIdx.x * CHUNK;

    for (int k = tid; k < NBUCK; k += 256) cnt[k] = 0;
    __syncthreads();
    // pass 1: per-bucket counts
    #pragma unroll
    for (int j = 0; j < CHUNK / 256; ++j) {
        int e = e0 + tid + j * 256;
        if (e < N_EDGES) atomicAdd(&cnt[edge_row[e] >> 8], 1);
    }
    __syncthreads();
    // exclusive scan (serial, once per block)
    if (tid == 0) {
        int run = 0;
        for (int k = 0; k < NBUCK; ++k) { pre[k] = run; run += cnt[k]; }
        pre[NBUCK] = run;
    }
    __syncthreads();
    // reserve global bucket space: one atomic per non-empty (block,bucket)
    for (int k = tid; k < NBUCK; k += 256)
        bas[k] = cnt[k] ? atomicAdd(&g_bucket_cur[k], cnt[k]) : 0;
    __syncthreads();
    for (int k = tid; k < NBUCK; k += 256) cnt[k] = 0;   // reuse as offsets
    __syncthreads();
    // pass 2: place records bucket-sorted in LDS
    #pragma unroll
    for (int j = 0; j < CHUNK / 256; ++j) {
        int e = e0 + tid + j * 256;
        if (e < N_EDGES) {
            int r = edge_row[e];
            int k = r >> 8;
            int o = atomicAdd(&cnt[k], 1);
            int2 pk;
            pk.x = edge_col[e] | ((r & 255) << 17);   // col:17b | row_local:8b
            pk.y = __float_as_int(edge_val[e]);
            rec[pre[k] + o] = pk;
        }
    }
    __syncthreads();
    // flush: consecutive i -> consecutive dest within bucket (bursts)
    const int total = pre[NBUCK];
    for (int i = tid; i < total; i += 256) {
        int lo = 0, hi = NBUCK;
        while (hi - lo > 1) {
            int mid = (lo + hi) >> 1;
            if (pre[mid] <= i) lo = mid; else hi = mid;
        }
        int k = lo;
        int dest = bas[k] + (i - pre[k]);
        int2 pk = rec[i];
        if (dest < CAPB) {
            g_binned[(size_t)k * CAPB + dest] = pk;
        } else {
            int o = atomicAdd(&g_novf, 1);
            if (o < OVF_MAX) {
                g_ovf_row[o] = (k << 8) | (pk.x >> 17);
                int2 ov; ov.x = pk.x & 0x1FFFF; ov.y = pk.y;
                g_ovf_edge[o] = ov;
            }
        }
    }
}

// ----------------------------- fused: phase B (fill padded CSR) || MFMA GEMM
// blocks [0, NBUCK): per-bucket fill — LDS cursors, stores land in a 128 KB
//                    L2-local window. blocks [NBUCK, +GEMM_BLOCKS): GEMM.
__launch_bounds__(256)
__global__ void gemm_fill_kernel(const float* __restrict__ x) {
    __shared__ float tile[4][16][68];
    __shared__ int cur[RPB];
    const int tid = threadIdx.x;
    const int b = blockIdx.x;

    if (b < NBUCK) {
        // ---------------- phase B: bucket -> padded CSR
        const int k = b;
        for (int i = tid; i < RPB; i += 256) cur[i] = 0;
        __syncthreads();
        const int nrec = min(g_bucket_cur[k], CAPB);
        const int2* src = &g_binned[(size_t)k * CAPB];
        for (int i = tid; i < nrec; i += 256) {
            int2 pk = src[i];
            int rl  = pk.x >> 17;
            int col = pk.x & 0x1FFFF;
            int slot = atomicAdd(&cur[rl], 1);        // LDS atomic
            int row = (k << 8) + rl;
            int2 o2; o2.x = col; o2.y = pk.y;
            if (slot < CAP) {
                g_pad[(size_t)row * CAP + slot] = o2;
            } else {
                int o = atomicAdd(&g_novf, 1);
                if (o < OVF_MAX) { g_ovf_row[o] = row; g_ovf_edge[o] = o2; }
            }
        }
        __syncthreads();
        for (int i = tid; i < RPB; i += 256) {
            int row = (k << 8) + i;
            if (row < N_NODES) g_cursor[row] = cur[i];
        }
    } else {
        // ---------------- GEMM: per-wave 16x64 tile, K=256, inline fp32->bf16
        const int g    = b - NBUCK;
        const int wave = tid >> 6;
        const int lane = tid & 63;
        const int m0   = g * 16;
        const int n0   = wave * 64;
        const int lm   = lane & 15;
        const int q    = lane >> 4;

        const unsigned short* B = g_wt;
        f32x4 acc0 = {}, acc1 = {}, acc2 = {}, acc3 = {};

        #pragma unroll
        for (int k0 = 0; k0 < D; k0 += 32) {
            const float* Arow = &x[(size_t)(m0 + lm) * D + k0 + q * 8];
            float4 f0 = *(const float4*)&Arow[0];
            float4 f1 = *(const float4*)&Arow[4];
            union { bf16x8 v; unsigned short u[8]; } au;
            au.u[0] = f2bf(f0.x); au.u[1] = f2bf(f0.y);
            au.u[2] = f2bf(f0.z); au.u[3] = f2bf(f0.w);
            au.u[4] = f2bf(f1.x); au.u[5] = f2bf(f1.y);
            au.u[6] = f2bf(f1.z); au.u[7] = f2bf(f1.w);

            bf16x8 b0 = *(const bf16x8*)&B[(size_t)(n0 +  0 + lm) * D + k0 + q * 8];
            bf16x8 b1 = *(const bf16x8*)&B[(size_t)(n0 + 16 + lm) * D + k0 + q * 8];
            bf16x8 b2 = *(const bf16x8*)&B[(size_t)(n0 + 32 + lm) * D + k0 + q * 8];
            bf16x8 b3 = *(const bf16x8*)&B[(size_t)(n0 + 48 + lm) * D + k0 + q * 8];
            acc0 = __builtin_amdgcn_mfma_f32_16x16x32_bf16(au.v, b0, acc0, 0, 0, 0);
            acc1 = __builtin_amdgcn_mfma_f32_16x16x32_bf16(au.v, b1, acc1, 0, 0, 0);
            acc2 = __builtin_amdgcn_mfma_f32_16x16x32_bf16(au.v, b2, acc2, 0, 0, 0);
            acc3 = __builtin_amdgcn_mfma_f32_16x16x32_bf16(au.v, b3, acc3, 0, 0, 0);
        }

        #pragma unroll
        for (int r = 0; r < 4; ++r) {
            tile[wave][q * 4 + r][ 0 + lm] = acc0[r];
            tile[wave][q * 4 + r][16 + lm] = acc1[r];
            tile[wave][q * 4 + r][32 + lm] = acc2[r];
            tile[wave][q * 4 + r][48 + lm] = acc3[r];
        }
        const int row  = lane >> 2;
        const int cseg = (lane & 3) * 16;
        unsigned short outv[16];
        #pragma unroll
        for (int j = 0; j < 16; ++j)
            outv[j] = f2bf(tile[wave][row][cseg + j]);
        unsigned short* dst = &g_support[(size_t)(m0 + row) * D + n0 + cseg];
        *(uint4*)&dst[0] = *(const uint4*)&outv[0];
        *(uint4*)&dst[8] = *(const uint4*)&outv[8];
    }
}

// ---------------------------------------------------------------- SpMM
// One 128-thread block per row; thread t owns features 2t, 2t+1.
__launch_bounds__(128)
__global__ void spmm_kernel(float* __restrict__ out) {
    const int r = blockIdx.x;
    const int t = threadIdx.x;
    const int deg = g_cursor[r];
    const int dpad = min(deg, CAP);
    const long long* rowp = (const long long*)&g_pad[(size_t)r * CAP];
    const unsigned* sup = (const unsigned*)g_support;

    float a0 = 0.f, a1 = 0.f;
    int i = 0;
    for (; i + 3 < dpad; i += 4) {
        long long q0 = __builtin_nontemporal_load(&rowp[i]);
        long long q1 = __builtin_nontemporal_load(&rowp[i + 1]);
        long long q2 = __builtin_nontemporal_load(&rowp[i + 2]);
        long long q3 = __builtin_nontemporal_load(&rowp[i + 3]);
        unsigned p0 = sup[(size_t)(int)q0 * (D / 2) + t];
        unsigned p1 = sup[(size_t)(int)q1 * (D / 2) + t];
        unsigned p2 = sup[(size_t)(int)q2 * (D / 2) + t];
        unsigned p3 = sup[(size_t)(int)q3 * (D / 2) + t];
        float v0 = __int_as_float((int)(q0 >> 32));
        float v1 = __int_as_float((int)(q1 >> 32));
        float v2 = __int_as_float((int)(q2 >> 32));
        float v3 = __int_as_float((int)(q3 >> 32));
        a0 += v0 * __uint_as_float(p0 << 16);
        a1 += v0 * __uint_as_float(p0 & 0xffff0000u);
        a0 += v1 * __uint_as_float(p1 << 16);
        a1 += v1 * __uint_as_float(p1 & 0xffff0000u);
        a0 += v2 * __uint_as_float(p2 << 16);
        a1 += v2 * __uint_as_float(p2 & 0xffff0000u);
        a0 += v3 * __uint_as_float(p3 << 16);
        a1 += v3 * __uint_as_float(p3 & 0xffff0000u);
    }
    for (; i < dpad; ++i) {
        long long q0 = __builtin_nontemporal_load(&rowp[i]);
        float v0 = __int_as_float((int)(q0 >> 32));
        unsigned p0 = sup[(size_t)(int)q0 * (D / 2) + t];
        a0 += v0 * __uint_as_float(p0 << 16);
        a1 += v0 * __uint_as_float(p0 & 0xffff0000u);
    }
    const int novf = min(g_novf, OVF_MAX);
    if (novf > 0) {                        // correctness fallback (empty in practice)
        for (int j = 0; j < novf; ++j) {
            if (g_ovf_row[j] == r) {
                int2 e0 = g_ovf_edge[j];
                float v0 = __int_as_float(e0.y);
                unsigned p0 = sup[(size_t)e0.x * (D / 2) + t];
                a0 += v0 * __uint_as_float(p0 << 16);
                a1 += v0 * __uint_as_float(p0 & 0xffff0000u);
            }
        }
    }
    f32x2 o;
    o.x = fmaxf(a0, 0.f);
    o.y = fmaxf(a1, 0.f);
    __builtin_nontemporal_store(o, (f32x2*)&out[(size_t)r * D + 2 * t]);
}

// ---------------------------------------------------------------- launcher
extern "C" void kernel_launch(void* const* d_in, const int* in_sizes, int n_in,
                              void* d_out, int out_size, void* d_ws, size_t ws_size,
                              hipStream_t stream) {
    const float* x        = (const float*)d_in[0];
    const float* weight   = (const float*)d_in[1];
    const float* edge_val = (const float*)d_in[2];
    const int*   edge_row = (const int*)d_in[3];
    const int*   edge_col = (const int*)d_in[4];
    float* out = (float*)d_out;

    setup_kernel<<<64, 256, 0, stream>>>(weight);
    bin_kernel<<<NBLK_A, 256, 0, stream>>>(edge_val, edge_row, edge_col);
    gemm_fill_kernel<<<NBUCK + GEMM_BLOCKS, 256, 0, stream>>>(x);
    spmm_kernel<<<N_NODES, 128, 0, stream>>>(out);
}